// Round 1
// baseline (274.528 us; speedup 1.0000x reference)
//
#include <hip/hip_runtime.h>
#include <hip/hip_bf16.h>

#define HEADS 16
#define KEY   64
#define BB    2
#define SS    2048
#define DD    1024
#define NCOL  1024   // HEADS*KEY

typedef __attribute__((ext_vector_type(8))) short bf16x8;
typedef __attribute__((ext_vector_type(4))) float f32x4;
typedef __attribute__((ext_vector_type(8))) unsigned short u16x8;

typedef const __attribute__((address_space(1))) void* gas_ptr;
typedef __attribute__((address_space(3))) void* las_ptr;

__device__ __forceinline__ void gload_lds16(const void* g, void* l) {
  __builtin_amdgcn_global_load_lds((gas_ptr)g, (las_ptr)l, 16, 0, 0);
}

__device__ __forceinline__ unsigned short f2bf(float f) {
  unsigned u = __builtin_bit_cast(unsigned, f);
  u = (u + 0x7FFFu + ((u >> 16) & 1u)) >> 16;
  return (unsigned short)u;
}

__device__ __forceinline__ f32x4 mfma_bf16(bf16x8 a, bf16x8 b, f32x4 c) {
  return __builtin_amdgcn_mfma_f32_16x16x32_bf16(a, b, c, 0, 0, 0);
}

// ---------------- fp32 -> bf16 convert (8 elems/thread) ----------------
__global__ __launch_bounds__(256) void cvt_bf16(const float* __restrict__ in,
                                                unsigned short* __restrict__ out,
                                                int n8) {
  int i = blockIdx.x * blockDim.x + threadIdx.x;
  if (i >= n8) return;
  const float4* p = reinterpret_cast<const float4*>(in) + (size_t)i * 2;
  float4 a = p[0], b = p[1];
  u16x8 o;
  o[0] = f2bf(a.x); o[1] = f2bf(a.y); o[2] = f2bf(a.z); o[3] = f2bf(a.w);
  o[4] = f2bf(b.x); o[5] = f2bf(b.y); o[6] = f2bf(b.z); o[7] = f2bf(b.w);
  reinterpret_cast<u16x8*>(out)[i] = o;
}

// ---------------- W (K x N) fp32 -> W^T (N x K) bf16 ----------------
__global__ __launch_bounds__(1024) void trw(const float* __restrict__ W0,
                                            const float* __restrict__ W1,
                                            const float* __restrict__ W2,
                                            unsigned short* __restrict__ T0,
                                            unsigned short* __restrict__ T1,
                                            unsigned short* __restrict__ T2) {
  const float* W = blockIdx.z == 0 ? W0 : (blockIdx.z == 1 ? W1 : W2);
  unsigned short* T = blockIdx.z == 0 ? T0 : (blockIdx.z == 1 ? T1 : T2);
  __shared__ float tile[32][33];
  int tx = threadIdx.x, ty = threadIdx.y;
  tile[ty][tx] = W[(size_t)(blockIdx.y * 32 + ty) * DD + blockIdx.x * 32 + tx];
  __syncthreads();
  T[(size_t)(blockIdx.x * 32 + ty) * DD + blockIdx.y * 32 + tx] = f2bf(tile[tx][ty]);
}

// ---------------- projection GEMM: O(M,N) = X(M,K) * WT(N,K)^T, bf16 ----------------
// M=4096, N=1024, K=1024. 128x128 tile, BK=32, 4 waves, 16x16x32 MFMA.
__global__ __launch_bounds__(256) void gemm_proj(
    const unsigned short* __restrict__ X0, const unsigned short* __restrict__ X1,
    const unsigned short* __restrict__ X2,
    const unsigned short* __restrict__ W0, const unsigned short* __restrict__ W1,
    const unsigned short* __restrict__ W2,
    unsigned short* __restrict__ O0, unsigned short* __restrict__ O1,
    unsigned short* __restrict__ O2) {
  const unsigned short* X; const unsigned short* WT; unsigned short* O;
  if (blockIdx.z == 0)      { X = X0; WT = W0; O = O0; }
  else if (blockIdx.z == 1) { X = X1; WT = W1; O = O1; }
  else                      { X = X2; WT = W2; O = O2; }

  __shared__ __align__(16) unsigned short As[128 * 32];
  __shared__ __align__(16) unsigned short Bs[128 * 32];

  const int tid = threadIdx.x;
  const int w = tid >> 6, l = tid & 63;
  const int m0 = blockIdx.x * 128, n0 = blockIdx.y * 128;
  const int wm = (w >> 1) * 64, wn = (w & 1) * 64;
  const int g = l >> 4, c = l & 15;

  const int srow = tid >> 2;        // 0..63 (i adds 64)
  const int scol = (tid & 3) * 8;   // k element offset

  f32x4 acc[4][4] = {};

  for (int k0 = 0; k0 < DD; k0 += 32) {
#pragma unroll
    for (int i = 0; i < 2; ++i) {
      gload_lds16(X + (size_t)(m0 + i * 64 + srow) * DD + k0 + scol,
                  (char*)As + i * 4096 + w * 1024);
      gload_lds16(WT + (size_t)(n0 + i * 64 + srow) * DD + k0 + scol,
                  (char*)Bs + i * 4096 + w * 1024);
    }
    __syncthreads();
    bf16x8 af[4], bfr[4];
    const int kb = g * 8;
#pragma unroll
    for (int mi = 0; mi < 4; mi++)
      af[mi] = *reinterpret_cast<const bf16x8*>(&As[(wm + mi * 16 + c) * 32 + kb]);
#pragma unroll
    for (int ni = 0; ni < 4; ni++)
      bfr[ni] = *reinterpret_cast<const bf16x8*>(&Bs[(wn + ni * 16 + c) * 32 + kb]);
#pragma unroll
    for (int mi = 0; mi < 4; mi++)
#pragma unroll
      for (int ni = 0; ni < 4; ni++)
        acc[mi][ni] = mfma_bf16(af[mi], bfr[ni], acc[mi][ni]);
    __syncthreads();
  }

#pragma unroll
  for (int mi = 0; mi < 4; mi++)
#pragma unroll
    for (int ni = 0; ni < 4; ni++)
#pragma unroll
      for (int r = 0; r < 4; r++) {
        int row = m0 + wm + mi * 16 + g * 4 + r;
        int col = n0 + wn + ni * 16 + c;
        O[(size_t)row * NCOL + col] = f2bf(acc[mi][ni][r]);
      }
}

// ---------------- causal flash attention ----------------
// grid (S/64, H, B), 256 threads = 4 waves, wave w owns q rows q0+w*16..+15.
__global__ __launch_bounds__(256) void attn(const unsigned short* __restrict__ qw,
                                            const unsigned short* __restrict__ kw,
                                            const unsigned short* __restrict__ vw,
                                            float* __restrict__ out) {
  __shared__ __align__(16) unsigned short Ks[64 * 64];      // [kv][d], XOR-swizzled
  __shared__ __align__(16) unsigned short Vt[64 * 64];      // [d][kv], XOR-swizzled
  __shared__ __align__(16) unsigned short Plds[4][16 * 72]; // per-wave, padded

  const int tid = threadIdx.x, w = tid >> 6, l = tid & 63;
  const int q0 = blockIdx.x * 64, h = blockIdx.y, b = blockIdx.z;
  const int g = l >> 4, c = l & 15;

  // Q fragments (A operand): row = lane&15, k = (lane>>4)*8 + j (+32 for ks=1)
  const size_t qbase = ((size_t)(b * SS) + q0 + w * 16 + c) * NCOL + h * KEY;
  bf16x8 qf[2];
  qf[0] = *reinterpret_cast<const bf16x8*>(qw + qbase + g * 8);
  qf[1] = *reinterpret_cast<const bf16x8*>(qw + qbase + g * 8 + 32);

  f32x4 oacc[4] = {};
  float m[4], lsum[4];
#pragma unroll
  for (int r = 0; r < 4; r++) { m[r] = -1e30f; lsum[r] = 0.f; }

  // K staging geometry: lane dest row = j*32 + w*8 + (l>>3), colel = (l&7)*8.
  // Source column pre-swizzled so LDS reads use byte ^= ((row&7)<<4).
  const int krow_base = w * 8 + (l >> 3);
  const int kcol_sw = 8 * ((l & 7) ^ (l >> 3));
  // V transpose staging: thread reads V[vrow][vcol0..vcol0+15]
  const int vrow = tid >> 2;
  const int vcol0 = (tid & 3) * 16;

  const int kv_end = q0 + 64;
  for (int kv0 = 0; kv0 < kv_end; kv0 += 64) {
    // ---- stage K (async, swizzled source) ----
#pragma unroll
    for (int j = 0; j < 2; ++j)
      gload_lds16(kw + ((size_t)(b * SS) + kv0 + j * 32 + krow_base) * NCOL + h * KEY + kcol_sw,
                  (char*)Ks + j * 4096 + w * 1024);
    // ---- stage V transposed (swizzled dest) ----
    {
      const unsigned short* vsrc = vw + ((size_t)(b * SS) + kv0 + vrow) * NCOL + h * KEY + vcol0;
      u16x8 v0 = *reinterpret_cast<const u16x8*>(vsrc);
      u16x8 v1 = *reinterpret_cast<const u16x8*>(vsrc + 8);
#pragma unroll
      for (int e = 0; e < 8; e++) {
        int d0 = vcol0 + e, d1 = vcol0 + 8 + e;
        Vt[d0 * 64 + (vrow ^ ((d0 & 7) * 8))] = v0[e];
        Vt[d1 * 64 + (vrow ^ ((d1 & 7) * 8))] = v1[e];
      }
    }
    __syncthreads();

    // ---- S = Q K^T (per wave: 16 q x 64 kv) ----
    f32x4 sacc[4] = {};
#pragma unroll
    for (int t = 0; t < 4; t++) {
#pragma unroll
      for (int ks = 0; ks < 2; ks++) {
        int off = ((g | (ks << 2)) ^ (c & 7)) << 3;
        bf16x8 kf = *reinterpret_cast<const bf16x8*>(&Ks[(t * 16 + c) * 64 + off]);
        sacc[t] = mfma_bf16(qf[ks], kf, sacc[t]);
      }
    }

    // ---- online softmax ----
    float p[4][4], pm[4];
#pragma unroll
    for (int r = 0; r < 4; r++) pm[r] = -1e30f;
    const int qrow = q0 + w * 16 + g * 4;
#pragma unroll
    for (int t = 0; t < 4; t++) {
      int kv = kv0 + t * 16 + c;
#pragma unroll
      for (int r = 0; r < 4; r++) {
        float s = sacc[t][r] * 0.125f;
        if (kv > qrow + r) s = -1e30f;
        p[t][r] = s;
        pm[r] = fmaxf(pm[r], s);
      }
    }
#pragma unroll
    for (int r = 0; r < 4; r++) {
      float v = pm[r];
      v = fmaxf(v, __shfl_xor(v, 1));
      v = fmaxf(v, __shfl_xor(v, 2));
      v = fmaxf(v, __shfl_xor(v, 4));
      v = fmaxf(v, __shfl_xor(v, 8));
      float mn = fmaxf(m[r], v);
      float alpha = __expf(m[r] - mn);
      m[r] = mn;
      lsum[r] *= alpha;
#pragma unroll
      for (int t = 0; t < 4; t++) oacc[t][r] *= alpha;
    }
    float rs[4] = {0.f, 0.f, 0.f, 0.f};
#pragma unroll
    for (int t = 0; t < 4; t++)
#pragma unroll
      for (int r = 0; r < 4; r++) {
        float e = __expf(p[t][r] - m[r]);
        p[t][r] = e;
        rs[r] += e;
      }
#pragma unroll
    for (int r = 0; r < 4; r++) {
      float v = rs[r];
      v += __shfl_xor(v, 1);
      v += __shfl_xor(v, 2);
      v += __shfl_xor(v, 4);
      v += __shfl_xor(v, 8);
      lsum[r] += v;
    }

    // ---- P -> LDS (bf16), then PV ----
#pragma unroll
    for (int t = 0; t < 4; t++)
#pragma unroll
      for (int r = 0; r < 4; r++)
        Plds[w][(g * 4 + r) * 72 + t * 16 + c] = f2bf(p[t][r]);

    bf16x8 pf[2];
    pf[0] = *reinterpret_cast<const bf16x8*>(&Plds[w][c * 72 + g * 8]);
    pf[1] = *reinterpret_cast<const bf16x8*>(&Plds[w][c * 72 + g * 8 + 32]);
#pragma unroll
    for (int t = 0; t < 4; t++) {
#pragma unroll
      for (int ks = 0; ks < 2; ks++) {
        int off = ((g | (ks << 2)) ^ (c & 7)) << 3;
        bf16x8 vf = *reinterpret_cast<const bf16x8*>(&Vt[(t * 16 + c) * 64 + off]);
        oacc[t] = mfma_bf16(pf[ks], vf, oacc[t]);
      }
    }
    __syncthreads();
  }

  // ---- epilogue: normalize + store fp32 ----
#pragma unroll
  for (int r = 0; r < 4; r++) {
    float inv = 1.0f / lsum[r];
    int qrow = q0 + w * 16 + g * 4 + r;
    float* op = out + ((size_t)(b * SS) + qrow) * NCOL + h * KEY;
#pragma unroll
    for (int t = 0; t < 4; t++)
      op[t * 16 + c] = oacc[t][r] * inv;
  }
}

extern "C" void kernel_launch(void* const* d_in, const int* in_sizes, int n_in,
                              void* d_out, int out_size, void* d_ws, size_t ws_size,
                              hipStream_t stream) {
  const float* q  = (const float*)d_in[0];
  const float* k  = (const float*)d_in[1];
  const float* v  = (const float*)d_in[2];
  const float* Wq = (const float*)d_in[3];
  const float* Wk = (const float*)d_in[4];
  const float* Wv = (const float*)d_in[5];
  float* out = (float*)d_out;

  unsigned short* ws  = (unsigned short*)d_ws;
  const size_t ACT = (size_t)4 * 1024 * 1024;  // 4M elements per activation
  const size_t WEL = (size_t)1024 * 1024;      // 1M elements per weight
  unsigned short* qbf = ws;
  unsigned short* kbf = qbf + ACT;
  unsigned short* vbf = kbf + ACT;
  unsigned short* WqT = vbf + ACT;
  unsigned short* WkT = WqT + WEL;
  unsigned short* WvT = WkT + WEL;
  unsigned short* qwp = WvT + WEL;
  unsigned short* kwp = qwp + ACT;
  unsigned short* vwp = kwp + ACT;

  cvt_bf16<<<2048, 256, 0, stream>>>(q, qbf, 524288);
  cvt_bf16<<<2048, 256, 0, stream>>>(k, kbf, 524288);
  cvt_bf16<<<2048, 256, 0, stream>>>(v, vbf, 524288);
  trw<<<dim3(32, 32, 3), dim3(32, 32), 0, stream>>>(Wq, Wk, Wv, WqT, WkT, WvT);
  gemm_proj<<<dim3(32, 8, 3), 256, 0, stream>>>(qbf, kbf, vbf, WqT, WkT, WvT,
                                                qwp, kwp, vwp);
  attn<<<dim3(32, 16, 2), 256, 0, stream>>>(qwp, kwp, vwp, out);
}